// Round 13
// baseline (78.209 us; speedup 1.0000x reference)
//
#include <hip/hip_runtime.h>
#include <hip/hip_bf16.h>
#include <math.h>

typedef __attribute__((ext_vector_type(8))) short short8;   // bf16x8 MFMA frag
typedef __attribute__((ext_vector_type(4))) float floatx4;  // f32x4 MFMA acc
typedef float __attribute__((ext_vector_type(4))) f32x4;

static __device__ __forceinline__ unsigned short f2bf(float x) {
    union { float f; unsigned u; } v; v.f = x;
    unsigned r = v.u + 0x7FFFu + ((v.u >> 16) & 1u);
    return (unsigned short)(r >> 16);
}
static __device__ __forceinline__ unsigned packbf2(float a, float b) {
    return (unsigned)f2bf(a) | ((unsigned)f2bf(b) << 16);
}

// ---------------- Kernel 1: QKV projections via MFMA ----------------
__global__ __launch_bounds__(256) void qkv_kernel(
    const float* __restrict__ feat,
    const float* __restrict__ Wq, const float* __restrict__ bq,
    const float* __restrict__ Wk, const float* __restrict__ bk,
    const float* __restrict__ Wv, const float* __restrict__ bv,
    unsigned short* __restrict__ Qt, unsigned short* __restrict__ Kt,
    unsigned short* __restrict__ Vb, int N)
{
    const int n0 = blockIdx.x * 64;
    const int oh = blockIdx.y;           // o-half (64 o's)
    const int b  = blockIdx.z;
    const int t = threadIdx.x;
    const int w = t >> 6, lane = t & 63, g = lane >> 4, q = lane & 15;

    __shared__ __align__(16) unsigned ft[64 * 64];   // [n][c2 swz]
    __shared__ __align__(16) unsigned wl[64 * 64];   // [o_loc][c2 swz]

    const float* fb = feat + (size_t)b * 128 * N + n0;
    {
        int n = lane;
        int swz = (n & 7) << 2;
#pragma unroll
        for (int iter = 0; iter < 16; ++iter) {
            int c2 = iter * 4 + w;
            float x0 = fb[(size_t)(2 * c2) * N + n];
            float x1 = fb[(size_t)(2 * c2 + 1) * N + n];
            ft[n * 64 + (c2 ^ swz)] = packbf2(x0, x1);
        }
    }
    __syncthreads();

    short8 af[4];
    {
        int nl = w * 16 + q;
        const unsigned* base = ft + nl * 64;
        int swz = (nl & 7) << 2;
#pragma unroll
        for (int cs = 0; cs < 4; ++cs)
            af[cs] = *(const short8*)(base + ((cs * 16 + g * 4) ^ swz));
    }

    for (int p = 0; p < 3; ++p) {
        const float* W    = p == 0 ? Wq : (p == 1 ? Wk : Wv);
        const float* bias = p == 0 ? bq : (p == 1 ? bk : bv);
        const float* Wsrc = W + (size_t)oh * 64 * 128;
        __syncthreads();
        {
            int c2 = lane;
#pragma unroll
            for (int iter = 0; iter < 16; ++iter) {
                int ol = iter * 4 + w;
                float2 v = *(const float2*)(Wsrc + ol * 128 + c2 * 2);
                wl[ol * 64 + (c2 ^ ((ol & 7) << 2))] = packbf2(v.x, v.y);
            }
        }
        __syncthreads();

#pragma unroll
        for (int ot = 0; ot < 4; ++ot) {
            short8 wf[4];
            {
                const unsigned* basep = wl + (ot * 16 + q) * 64;
                int swz = (q & 7) << 2;
#pragma unroll
                for (int cs = 0; cs < 4; ++cs)
                    wf[cs] = *(const short8*)(basep + ((cs * 16 + g * 4) ^ swz));
            }
            floatx4 acc = {0.f, 0.f, 0.f, 0.f};
            if (p < 2) {
#pragma unroll
                for (int cs = 0; cs < 4; ++cs)
                    acc = __builtin_amdgcn_mfma_f32_16x16x32_bf16(af[cs], wf[cs], acc, 0, 0, 0);
                int o = oh * 64 + ot * 16 + q;
                float bo = bias[o];
                unsigned short* T = (p == 0 ? Qt : Kt) + (size_t)b * N * 128;
#pragma unroll
                for (int rr = 0; rr < 4; ++rr) {
                    int n = n0 + w * 16 + g * 4 + rr;
                    T[(size_t)n * 128 + o] = f2bf(acc[rr] + bo);
                }
            } else {
#pragma unroll
                for (int cs = 0; cs < 4; ++cs)
                    acc = __builtin_amdgcn_mfma_f32_16x16x32_bf16(wf[cs], af[cs], acc, 0, 0, 0);
                int n = n0 + w * 16 + q;
#pragma unroll
                for (int rr = 0; rr < 4; ++rr) {
                    int o = oh * 64 + ot * 16 + g * 4 + rr;
                    Vb[((size_t)b * 128 + o) * N + n] = f2bf(acc[rr] + bias[o]);
                }
            }
        }
    }
}

// ---------------- Kernel 2: flash attention v4 — counted vmcnt pipeline ----------------
// Block: 128 o (8 waves x 16 o), 32-i steps, ONE raw s_barrier per step, NEVER
// vmcnt(0) in loop. K/V: 3-buffer block-shared staging. att: 3-buffer WAVE-PRIVATE
// strips (each wave stages its own 16 rows), depth-2 prefetch.
// Iter t: issue kv(t+1), att(t+2); s_waitcnt vmcnt(6); s_barrier; compute(t).
#define STAGE_KV(KBASE, VBASE, IB)                                                         \
    __builtin_amdgcn_global_load_lds(                                                      \
        (const void*)(Kb + (size_t)((IB) + kr) * 128 + (kj << 3)),                         \
        (void*)((char*)(KBASE) + (w << 10) + (lane << 4)), 16, 0, 0);                      \
    __builtin_amdgcn_global_load_lds(                                                      \
        (const void*)(Vbp + (size_t)vc * N + (IB) + (vj << 3)),                            \
        (void*)((char*)(VBASE) + (w << 10) + (lane << 4)), 16, 0, 0);

#define STAGE_ATT(ABASE, IB)                                                               \
    __builtin_amdgcn_global_load_lds(                                                      \
        (const void*)(asrc + (IB)),                                                        \
        (void*)((char*)(ABASE) + (lane << 4)), 16, 0, 0);                                  \
    __builtin_amdgcn_global_load_lds(                                                      \
        (const void*)(asrc + (size_t)8 * N + (IB)),                                       \
        (void*)((char*)(ABASE) + 1024 + (lane << 4)), 16, 0, 0);

#define ATT_STEP(KI, VI, AI)                                                               \
  {                                                                                        \
    const unsigned short* Kl = &K_l[KI][0];                                                \
    floatx4 s0 = {0.f,0.f,0.f,0.f}, s1 = {0.f,0.f,0.f,0.f};                                \
    _Pragma("unroll")                                                                      \
    for (int cs = 0; cs < 4; ++cs) {                                                       \
        short8 kf0 = *(const short8*)(Kl + q * 128 + ((((cs << 2) + g) ^ (q & 7)) << 3));  \
        short8 kf1 = *(const short8*)(Kl + (16 + q) * 128 + ((((cs << 2) + g) ^ (q & 7)) << 3)); \
        s0 = __builtin_amdgcn_mfma_f32_16x16x32_bf16(kf0, qf[cs], s0, 0, 0, 0);            \
        s1 = __builtin_amdgcn_mfma_f32_16x16x32_bf16(kf1, qf[cs], s1, 0, 0, 0);            \
    }                                                                                      \
    const float* Al = &att_l[AI][0] + w * 512;                                             \
    f32x4 av0 = *(const f32x4*)(Al + q * 32 + ((g ^ (q & 7)) << 2));                       \
    f32x4 av1 = *(const f32x4*)(Al + q * 32 + (((4 + g) ^ (q & 7)) << 2));                 \
    float p0 = __expf(s0[0] * rsd * av0[0]);                                               \
    float p1 = __expf(s0[1] * rsd * av0[1]);                                               \
    float p2 = __expf(s0[2] * rsd * av0[2]);                                               \
    float p3 = __expf(s0[3] * rsd * av0[3]);                                               \
    float p4 = __expf(s1[0] * rsd * av1[0]);                                               \
    float p5 = __expf(s1[1] * rsd * av1[1]);                                               \
    float p6 = __expf(s1[2] * rsd * av1[2]);                                               \
    float p7 = __expf(s1[3] * rsd * av1[3]);                                               \
    l0 += ((p0 + p1) + (p2 + p3)) + ((p4 + p5) + (p6 + p7));                               \
    *(uint2*)pw0 = make_uint2(packbf2(p0, p1), packbf2(p2, p3));                           \
    *(uint2*)pw1 = make_uint2(packbf2(p4, p5), packbf2(p6, p7));                           \
    short8 pf = *(const short8*)pr;                                                        \
    const unsigned short* Vl = &V_l[VI][0];                                                \
    _Pragma("unroll")                                                                      \
    for (int ct = 0; ct < 8; ++ct) {                                                       \
        int c = ct * 16 + q;                                                               \
        short8 vf = *(const short8*)(Vl + c * 32 + ((g ^ ((c >> 1) & 3)) << 3));           \
        macc[ct] = __builtin_amdgcn_mfma_f32_16x16x32_bf16(vf, pf, macc[ct], 0, 0, 0);     \
    }                                                                                      \
  }

__global__ __launch_bounds__(512) void attn_kernel(
    const unsigned short* __restrict__ Qt, const unsigned short* __restrict__ Kt,
    const unsigned short* __restrict__ Vb, const float* __restrict__ att,
    float* __restrict__ pmsg, float* __restrict__ pl, int N, int bs)
{
    const int b = blockIdx.z;
    const int split = blockIdx.y;
    const int NSplit = gridDim.y;
    const int obase = blockIdx.x * 128;
    const int t = threadIdx.x;
    const int w = t >> 6, lane = t & 63, g = lane >> 4, q = lane & 15;

    __shared__ __align__(16) unsigned short K_l[3][32 * 128];  // 24 KB [i][c] swz
    __shared__ __align__(16) unsigned short V_l[3][128 * 32];  // 24 KB [c][i] swz
    __shared__ __align__(16) float att_l[3][128 * 32];         // 48 KB wave strips
    __shared__ __align__(16) unsigned short P_l[8][16 * 32];   // 8 KB wave-private

    const unsigned short* Qb  = Qt + (size_t)b * N * 128;
    const unsigned short* Kb  = Kt + (size_t)b * N * 128;
    const unsigned short* Vbp = Vb + (size_t)b * 128 * N;
    const float* attb = att + (size_t)b * N * N;
    const int wo = obase + w * 16;                 // wave's o-base

    // Q B-frags for o = wo + q
    short8 qf[4];
#pragma unroll
    for (int cs = 0; cs < 4; ++cs)
        qf[cs] = *(const short8*)(Qb + (size_t)(wo + q) * 128 + cs * 32 + g * 8);
    // drain Q loads so the loop's vmcnt counting is exact
    asm volatile("s_waitcnt vmcnt(0)" ::: "memory");

    floatx4 macc[8];
#pragma unroll
    for (int ct = 0; ct < 8; ++ct) macc[ct] = (floatx4){0.f, 0.f, 0.f, 0.f};
    float l0 = 0.f;
    const float rsd = 0.08838834764831845f;   // 1/sqrt(128)

    const int irange = N / NSplit;
    const int i0 = split * irange;
    const int nsteps = irange >> 5;

    // staging lane decomposition (pre-swizzled global chunk)
    const int kr = (w << 2) + (lane >> 4);           // K row (i) 0..31
    const int kj = (lane & 15) ^ (kr & 7);           // 16B chunk of 16
    const int vc = (w << 4) + (lane >> 2);           // V row (c) 0..127
    const int vj = (lane & 3) ^ ((vc >> 1) & 3);     // 16B chunk of 4
    // att: wave stages ITS OWN rows wo..wo+15. lane -> row r=(h<<3)+(lane>>3),
    // chunk j=lane&7, content pre-swizzled j^(r&7) ((8+r)&7 == r&7).
    const float* asrc = attb + (size_t)(wo + (lane >> 3)) * N
                      + (((lane & 7) ^ ((lane >> 3) & 7)) << 2);

    // wave-private P strip ([o=q][i 32] bf16, 16B-unit XOR (q&3) swizzle)
    unsigned short* Pw = &P_l[w][0];
    char* pw0 = (char*)Pw + q * 64 + ((((g >> 1)) ^ (q & 3)) << 4) + ((g & 1) << 3);
    char* pw1 = (char*)Pw + q * 64 + (((2 + (g >> 1)) ^ (q & 3)) << 4) + ((g & 1) << 3);
    const char* pr = (const char*)Pw + q * 64 + ((g ^ (q & 3)) << 4);

    const int ibmax = N - 32;

    // prologue: att(0), kv(0), att(1)  [6 loads outstanding]
    {
        int ia0 = i0;
        int ia1 = i0 + 32 > ibmax ? ibmax : i0 + 32;
        STAGE_ATT(&att_l[0][0] + w * 512, ia0)
        STAGE_KV(&K_l[0][0], &V_l[0][0], i0)
        STAGE_ATT(&att_l[1][0] + w * 512, ia1)
    }

    int c0 = 0, c1 = 1, c2 = 2;
    for (int st = 0; st < nsteps; ++st) {
        int ibk = i0 + (st + 1) * 32; if (ibk > ibmax) ibk = ibmax;
        int iba = i0 + (st + 2) * 32; if (iba > ibmax) iba = ibmax;
        STAGE_KV(&K_l[c1][0], &V_l[c1][0], ibk)       // kv(t+1) -> buf(t-2): safe after prev barrier
        STAGE_ATT(&att_l[c2][0] + w * 512, iba)       // att(t+2): wave-private
        asm volatile("s_waitcnt vmcnt(6)" ::: "memory");  // kv(t)+att(t) done; 6 stay in flight
        __builtin_amdgcn_s_barrier();                 // all threads' kv(t) staged
        __builtin_amdgcn_sched_barrier(0);
        ATT_STEP(c0, c0, c0)
        int tmp = c0; c0 = c1; c1 = c2; c2 = tmp;
    }
    asm volatile("s_waitcnt vmcnt(0)" ::: "memory");  // drain tail prefetches

    // partial denominator (wave-private o's)
    l0 += __shfl_xor(l0, 16);
    l0 += __shfl_xor(l0, 32);
    if (lane < 16)
        pl[(size_t)(split * bs + b) * N + wo + lane] = l0;

    // partial message: wave-exclusive (c, o) -> direct stores
    float* pbase = pmsg + (size_t)(split * bs + b) * 128 * N;
#pragma unroll
    for (int ct = 0; ct < 8; ++ct) {
        int c = ct * 16 + g * 4;
#pragma unroll
        for (int r = 0; r < 4; ++r)
            pbase[(size_t)(c + r) * N + wo + q] = macc[ct][r];
    }
}

// ---------------- Kernel 3: fused NSPLIT-way merge + MLP + residual ----------------
template<int NSPLIT>
__global__ __launch_bounds__(256) void mlp_kernel(
    const float* __restrict__ pmsg, const float* __restrict__ pl,
    const float* __restrict__ feat,
    const float* __restrict__ W1, const float* __restrict__ b1,
    const float* __restrict__ g1, const float* __restrict__ be1,
    const float* __restrict__ m1, const float* __restrict__ v1,
    const float* __restrict__ W2, const float* __restrict__ b2,
    const float* __restrict__ g2, const float* __restrict__ be2,
    const float* __restrict__ m2, const float* __restrict__ v2,
    const float* __restrict__ W3, const float* __restrict__ b3,
    float* __restrict__ out, int N, int bs)
{
    const int b = blockIdx.y;
    const int nb = blockIdx.x * 32;
    const int t = threadIdx.x;
    const int n_l = t & 31, og = t >> 5;   // 8 groups
    const float EPS = 1e-5f;

    __shared__ float msg_s[128][32];
    __shared__ float h1_s[64][32];
    __shared__ float h2_s[64][32];
    __shared__ float linv_s[32];

    if (t < 32) {
        float s = 0.f;
#pragma unroll
        for (int k = 0; k < NSPLIT; ++k)
            s += pl[(size_t)(k * bs + b) * N + nb + t];
        linv_s[t] = 1.f / s;
    }
    __syncthreads();

    // phase 0: merge partials into LDS msg tile (float4, fully unrolled)
#pragma unroll
    for (int r = 0; r < 4; ++r) {
        int idx = t + r * 256;            // 0..1023 float4 slots
        int c = idx >> 3, n4 = (idx & 7) * 4;
        float4 s = make_float4(0.f, 0.f, 0.f, 0.f);
#pragma unroll
        for (int k = 0; k < NSPLIT; ++k) {
            float4 v = *(const float4*)(pmsg + (size_t)(k * bs + b) * 128 * N
                                        + (size_t)c * N + nb + n4);
            s.x += v.x; s.y += v.y; s.z += v.z; s.w += v.w;
        }
        float4 li = *(const float4*)&linv_s[n4];
        msg_s[c][n4 + 0] = s.x * li.x;
        msg_s[c][n4 + 1] = s.y * li.y;
        msg_s[c][n4 + 2] = s.z * li.z;
        msg_s[c][n4 + 3] = s.w * li.w;
    }
    __syncthreads();

    float acc[8];
#pragma unroll
    for (int i = 0; i < 8; ++i) acc[i] = 0.f;
    for (int c4 = 0; c4 < 128; c4 += 4) {
        float f0 = msg_s[c4 + 0][n_l], f1 = msg_s[c4 + 1][n_l];
        float f2 = msg_s[c4 + 2][n_l], f3 = msg_s[c4 + 3][n_l];
#pragma unroll
        for (int oi = 0; oi < 8; ++oi) {
            float4 wv = *(const float4*)(W1 + (og * 8 + oi) * 128 + c4);
            acc[oi] += wv.x * f0 + wv.y * f1 + wv.z * f2 + wv.w * f3;
        }
    }
#pragma unroll
    for (int oi = 0; oi < 8; ++oi) {
        int o = og * 8 + oi;
        float inv = g1[o] / sqrtf(v1[o] + EPS);
        float val = (acc[oi] + b1[o]) * inv + (be1[o] - m1[o] * inv);
        h1_s[o][n_l] = fmaxf(val, 0.f);
    }
    __syncthreads();

    float acc2[8];
#pragma unroll
    for (int i = 0; i < 8; ++i) acc2[i] = 0.f;
    for (int c4 = 0; c4 < 64; c4 += 4) {
        float f0 = h1_s[c4 + 0][n_l], f1 = h1_s[c4 + 1][n_l];
        float f2 = h1_s[c4 + 2][n_l], f3 = h1_s[c4 + 3][n_l];
#pragma unroll
        for (int oi = 0; oi < 8; ++oi) {
            float4 wv = *(const float4*)(W2 + (og * 8 + oi) * 64 + c4);
            acc2[oi] += wv.x * f0 + wv.y * f1 + wv.z * f2 + wv.w * f3;
        }
    }
#pragma unroll
    for (int oi = 0; oi < 8; ++oi) {
        int o = og * 8 + oi;
        float inv = g2[o] / sqrtf(v2[o] + EPS);
        float val = (acc2[oi] + b2[o]) * inv + (be2[o] - m2[o] * inv);
        h2_s[o][n_l] = fmaxf(val, 0.f);
    }
    __syncthreads();

    float acc3[16];
#pragma unroll
    for (int i = 0; i < 16; ++i) acc3[i] = 0.f;
    for (int c4 = 0; c4 < 64; c4 += 4) {
        float f0 = h2_s[c4 + 0][n_l], f1 = h2_s[c4 + 1][n_l];
        float f2 = h2_s[c4 + 2][n_l], f3 = h2_s[c4 + 3][n_l];
#pragma unroll
        for (int oi = 0; oi < 16; ++oi) {
            float4 wv = *(const float4*)(W3 + (og * 16 + oi) * 64 + c4);
            acc3[oi] += wv.x * f0 + wv.y * f1 + wv.z * f2 + wv.w * f3;
        }
    }
#pragma unroll
    for (int oi = 0; oi < 16; ++oi) {
        int o = og * 16 + oi;
        size_t idx = (size_t)(b * 128 + o) * N + nb + n_l;
        out[idx] = feat[idx] + acc3[oi] + b3[o];
    }
}

extern "C" void kernel_launch(void* const* d_in, const int* in_sizes, int n_in,
                              void* d_out, int out_size, void* d_ws, size_t ws_size,
                              hipStream_t stream)
{
    const float* feat = (const float*)d_in[0];
    const float* att  = (const float*)d_in[1];
    const float* Wq = (const float*)d_in[2];  const float* bq = (const float*)d_in[3];
    const float* Wk = (const float*)d_in[4];  const float* bk = (const float*)d_in[5];
    const float* Wv = (const float*)d_in[6];  const float* bv = (const float*)d_in[7];
    const float* W1 = (const float*)d_in[8];  const float* b1 = (const float*)d_in[9];
    const float* g1 = (const float*)d_in[10]; const float* be1 = (const float*)d_in[11];
    const float* m1 = (const float*)d_in[12]; const float* v1 = (const float*)d_in[13];
    const float* W2 = (const float*)d_in[14]; const float* b2 = (const float*)d_in[15];
    const float* g2 = (const float*)d_in[16]; const float* be2 = (const float*)d_in[17];
    const float* m2 = (const float*)d_in[18]; const float* v2 = (const float*)d_in[19];
    const float* W3 = (const float*)d_in[20]; const float* b3 = (const float*)d_in[21];

    long long bsN = (long long)in_sizes[0] / 128;   // bs*N
    long long NN  = (long long)in_sizes[1];         // bs*N*N
    int N  = (int)(NN / bsN);
    int bs = (int)(bsN / N);

    // workspace layout (NSplit adaptive to ws_size; prefer 4 -> grid 256 = 1 block/CU)
    size_t qkvBytes = (size_t)3 * bs * N * 128 * 2;
    int NSplit = 4;
    while (NSplit > 1) {
        size_t need = qkvBytes + (size_t)NSplit * bs * 128 * N * 4
                    + (size_t)NSplit * bs * N * 4;
        if (need <= ws_size) break;
        NSplit >>= 1;
    }

    char* ws = (char*)d_ws;
    unsigned short* Qt = (unsigned short*)ws;            // bs*N*128 bf16
    unsigned short* Kt = Qt + (size_t)bs * N * 128;      // bs*N*128 bf16
    unsigned short* Vb = Kt + (size_t)bs * N * 128;      // bs*128*N bf16
    float* pmsg = (float*)(Vb + (size_t)bs * N * 128);   // NSplit*bs*128*N f32
    float* pl   = pmsg + (size_t)NSplit * bs * 128 * N;  // NSplit*bs*N f32

    dim3 grid1(N / 64, 2, bs);
    qkv_kernel<<<grid1, 256, 0, stream>>>(feat, Wq, bq, Wk, bk, Wv, bv, Qt, Kt, Vb, N);

    dim3 grid2(N / 128, NSplit, bs);
    attn_kernel<<<grid2, 512, 0, stream>>>(Qt, Kt, Vb, att, pmsg, pl, N, bs);

    dim3 grid3(N / 32, bs);
    switch (NSplit) {
    case 4:
        mlp_kernel<4><<<grid3, 256, 0, stream>>>(pmsg, pl, feat,
            W1, b1, g1, be1, m1, v1, W2, b2, g2, be2, m2, v2, W3, b3,
            (float*)d_out, N, bs);
        break;
    case 2:
        mlp_kernel<2><<<grid3, 256, 0, stream>>>(pmsg, pl, feat,
            W1, b1, g1, be1, m1, v1, W2, b2, g2, be2, m2, v2, W3, b3,
            (float*)d_out, N, bs);
        break;
    default:
        mlp_kernel<1><<<grid3, 256, 0, stream>>>(pmsg, pl, feat,
            W1, b1, g1, be1, m1, v1, W2, b2, g2, be2, m2, v2, W3, b3,
            (float*)d_out, N, bs);
        break;
    }
}

// Round 14
// 75.148 us; speedup vs baseline: 1.0407x; 1.0407x over previous
//
#include <hip/hip_runtime.h>
#include <hip/hip_bf16.h>
#include <math.h>

typedef __attribute__((ext_vector_type(8))) short short8;   // bf16x8 MFMA frag
typedef __attribute__((ext_vector_type(4))) float floatx4;  // f32x4 MFMA acc
typedef float __attribute__((ext_vector_type(4))) f32x4;

static __device__ __forceinline__ unsigned short f2bf(float x) {
    union { float f; unsigned u; } v; v.f = x;
    unsigned r = v.u + 0x7FFFu + ((v.u >> 16) & 1u);
    return (unsigned short)(r >> 16);
}
static __device__ __forceinline__ unsigned packbf2(float a, float b) {
    return (unsigned)f2bf(a) | ((unsigned)f2bf(b) << 16);
}

// ---------------- Kernel 1: QKV projections via MFMA ----------------
__global__ __launch_bounds__(256) void qkv_kernel(
    const float* __restrict__ feat,
    const float* __restrict__ Wq, const float* __restrict__ bq,
    const float* __restrict__ Wk, const float* __restrict__ bk,
    const float* __restrict__ Wv, const float* __restrict__ bv,
    unsigned short* __restrict__ Qt, unsigned short* __restrict__ Kt,
    unsigned short* __restrict__ Vb, int N)
{
    const int n0 = blockIdx.x * 64;
    const int oh = blockIdx.y;           // o-half (64 o's)
    const int b  = blockIdx.z;
    const int t = threadIdx.x;
    const int w = t >> 6, lane = t & 63, g = lane >> 4, q = lane & 15;

    __shared__ __align__(16) unsigned ft[64 * 64];   // [n][c2 swz]
    __shared__ __align__(16) unsigned wl[64 * 64];   // [o_loc][c2 swz]

    const float* fb = feat + (size_t)b * 128 * N + n0;
    {
        int n = lane;
        int swz = (n & 7) << 2;
#pragma unroll
        for (int iter = 0; iter < 16; ++iter) {
            int c2 = iter * 4 + w;
            float x0 = fb[(size_t)(2 * c2) * N + n];
            float x1 = fb[(size_t)(2 * c2 + 1) * N + n];
            ft[n * 64 + (c2 ^ swz)] = packbf2(x0, x1);
        }
    }
    __syncthreads();

    short8 af[4];
    {
        int nl = w * 16 + q;
        const unsigned* base = ft + nl * 64;
        int swz = (nl & 7) << 2;
#pragma unroll
        for (int cs = 0; cs < 4; ++cs)
            af[cs] = *(const short8*)(base + ((cs * 16 + g * 4) ^ swz));
    }

    for (int p = 0; p < 3; ++p) {
        const float* W    = p == 0 ? Wq : (p == 1 ? Wk : Wv);
        const float* bias = p == 0 ? bq : (p == 1 ? bk : bv);
        const float* Wsrc = W + (size_t)oh * 64 * 128;
        __syncthreads();
        {
            int c2 = lane;
#pragma unroll
            for (int iter = 0; iter < 16; ++iter) {
                int ol = iter * 4 + w;
                float2 v = *(const float2*)(Wsrc + ol * 128 + c2 * 2);
                wl[ol * 64 + (c2 ^ ((ol & 7) << 2))] = packbf2(v.x, v.y);
            }
        }
        __syncthreads();

#pragma unroll
        for (int ot = 0; ot < 4; ++ot) {
            short8 wf[4];
            {
                const unsigned* basep = wl + (ot * 16 + q) * 64;
                int swz = (q & 7) << 2;
#pragma unroll
                for (int cs = 0; cs < 4; ++cs)
                    wf[cs] = *(const short8*)(basep + ((cs * 16 + g * 4) ^ swz));
            }
            floatx4 acc = {0.f, 0.f, 0.f, 0.f};
            if (p < 2) {
#pragma unroll
                for (int cs = 0; cs < 4; ++cs)
                    acc = __builtin_amdgcn_mfma_f32_16x16x32_bf16(af[cs], wf[cs], acc, 0, 0, 0);
                int o = oh * 64 + ot * 16 + q;
                float bo = bias[o];
                unsigned short* T = (p == 0 ? Qt : Kt) + (size_t)b * N * 128;
#pragma unroll
                for (int rr = 0; rr < 4; ++rr) {
                    int n = n0 + w * 16 + g * 4 + rr;
                    T[(size_t)n * 128 + o] = f2bf(acc[rr] + bo);
                }
            } else {
#pragma unroll
                for (int cs = 0; cs < 4; ++cs)
                    acc = __builtin_amdgcn_mfma_f32_16x16x32_bf16(wf[cs], af[cs], acc, 0, 0, 0);
                int n = n0 + w * 16 + q;
#pragma unroll
                for (int rr = 0; rr < 4; ++rr) {
                    int o = oh * 64 + ot * 16 + g * 4 + rr;
                    Vb[((size_t)b * 128 + o) * N + n] = f2bf(acc[rr] + bias[o]);
                }
            }
        }
    }
}

// ---------------- Kernel 2: block-cooperative flash attention v3.1 ----------------
// r12 structure (best measured): 128 o (8 waves x 16 o), 32-i steps, one
// __syncthreads/step, all streams staged at STEP START via global_load_lds.
// v3.1: v_cvt_pk_bf16_f32 for P pack (shortens QK->PV VALU chain) + s_setprio
// around MFMA clusters.
#define STAGE_ALL(BUF, IB)                                                                 \
    __builtin_amdgcn_global_load_lds(                                                      \
        (const void*)(Kb + (size_t)((IB) + kr) * 128 + (kj << 3)),                         \
        (void*)((char*)&K_l[BUF][0] + (w << 10) + (lane << 4)), 16, 0, 0);                 \
    __builtin_amdgcn_global_load_lds(                                                      \
        (const void*)(Vbp + (size_t)vc * N + (IB) + (vj << 3)),                            \
        (void*)((char*)&V_l[BUF][0] + (w << 10) + (lane << 4)), 16, 0, 0);                 \
    __builtin_amdgcn_global_load_lds(                                                      \
        (const void*)(arp0 + (IB) + (aj << 2)),                                            \
        (void*)((char*)&att_l[BUF][0] + (w << 10) + (lane << 4)), 16, 0, 0);               \
    __builtin_amdgcn_global_load_lds(                                                      \
        (const void*)(arp1 + (IB) + (aj << 2)),                                            \
        (void*)((char*)&att_l[BUF][0] + 8192 + (w << 10) + (lane << 4)), 16, 0, 0);

#define ATT_STEP(BUF)                                                                      \
  {                                                                                        \
    const unsigned short* Kl = &K_l[BUF][0];                                               \
    floatx4 s0 = {0.f,0.f,0.f,0.f}, s1 = {0.f,0.f,0.f,0.f};                                \
    __builtin_amdgcn_s_setprio(1);                                                         \
    _Pragma("unroll")                                                                      \
    for (int cs = 0; cs < 4; ++cs) {                                                       \
        short8 kf0 = *(const short8*)(Kl + q * 128 + ((((cs << 2) + g) ^ (q & 7)) << 3));  \
        short8 kf1 = *(const short8*)(Kl + (16 + q) * 128 + ((((cs << 2) + g) ^ (q & 7)) << 3)); \
        s0 = __builtin_amdgcn_mfma_f32_16x16x32_bf16(kf0, qf[cs], s0, 0, 0, 0);            \
        s1 = __builtin_amdgcn_mfma_f32_16x16x32_bf16(kf1, qf[cs], s1, 0, 0, 0);            \
    }                                                                                      \
    __builtin_amdgcn_s_setprio(0);                                                         \
    const float* Al = &att_l[BUF][0];                                                      \
    f32x4 av0 = *(const f32x4*)(Al + (w * 16 + q) * 32 + ((g ^ (q & 7)) << 2));            \
    f32x4 av1 = *(const f32x4*)(Al + (w * 16 + q) * 32 + (((4 + g) ^ (q & 7)) << 2));      \
    float p0 = __expf(s0[0] * rsd * av0[0]);                                               \
    float p1 = __expf(s0[1] * rsd * av0[1]);                                               \
    float p2 = __expf(s0[2] * rsd * av0[2]);                                               \
    float p3 = __expf(s0[3] * rsd * av0[3]);                                               \
    float p4 = __expf(s1[0] * rsd * av1[0]);                                               \
    float p5 = __expf(s1[1] * rsd * av1[1]);                                               \
    float p6 = __expf(s1[2] * rsd * av1[2]);                                               \
    float p7 = __expf(s1[3] * rsd * av1[3]);                                               \
    l0 += ((p0 + p1) + (p2 + p3)) + ((p4 + p5) + (p6 + p7));                               \
    unsigned u01, u23, u45, u67;                                                           \
    asm("v_cvt_pk_bf16_f32 %0, %1, %2" : "=v"(u01) : "v"(p0), "v"(p1));                    \
    asm("v_cvt_pk_bf16_f32 %0, %1, %2" : "=v"(u23) : "v"(p2), "v"(p3));                    \
    asm("v_cvt_pk_bf16_f32 %0, %1, %2" : "=v"(u45) : "v"(p4), "v"(p5));                    \
    asm("v_cvt_pk_bf16_f32 %0, %1, %2" : "=v"(u67) : "v"(p6), "v"(p7));                    \
    *(uint2*)pw0 = make_uint2(u01, u23);                                                   \
    *(uint2*)pw1 = make_uint2(u45, u67);                                                   \
    short8 pf = *(const short8*)pr;                                                        \
    const unsigned short* Vl = &V_l[BUF][0];                                               \
    __builtin_amdgcn_s_setprio(1);                                                         \
    _Pragma("unroll")                                                                      \
    for (int ct = 0; ct < 8; ++ct) {                                                       \
        int c = ct * 16 + q;                                                               \
        short8 vf = *(const short8*)(Vl + c * 32 + ((g ^ ((c >> 1) & 3)) << 3));           \
        macc[ct] = __builtin_amdgcn_mfma_f32_16x16x32_bf16(vf, pf, macc[ct], 0, 0, 0);     \
    }                                                                                      \
    __builtin_amdgcn_s_setprio(0);                                                         \
  }

__global__ __launch_bounds__(512) void attn_kernel(
    const unsigned short* __restrict__ Qt, const unsigned short* __restrict__ Kt,
    const unsigned short* __restrict__ Vb, const float* __restrict__ att,
    float* __restrict__ pmsg, float* __restrict__ pl, int N, int bs)
{
    const int b = blockIdx.z;
    const int split = blockIdx.y;
    const int NSplit = gridDim.y;
    const int obase = blockIdx.x * 128;
    const int t = threadIdx.x;
    const int w = t >> 6, lane = t & 63, g = lane >> 4, q = lane & 15;

    __shared__ __align__(16) unsigned short K_l[2][32 * 128];  // 16 KB [i][c] swz
    __shared__ __align__(16) unsigned short V_l[2][128 * 32];  // 16 KB [c][i] swz
    __shared__ __align__(16) float att_l[2][128 * 32];         // 32 KB [o][i] swz
    __shared__ __align__(16) unsigned short P_l[8][16 * 32];   // 8 KB wave-private

    const unsigned short* Qb  = Qt + (size_t)b * N * 128;
    const unsigned short* Kb  = Kt + (size_t)b * N * 128;
    const unsigned short* Vbp = Vb + (size_t)b * 128 * N;
    const float* attb = att + (size_t)b * N * N;
    const int wo = obase + w * 16;                 // wave's o-base

    // Q B-frags for o = wo + q
    short8 qf[4];
#pragma unroll
    for (int cs = 0; cs < 4; ++cs)
        qf[cs] = *(const short8*)(Qb + (size_t)(wo + q) * 128 + cs * 32 + g * 8);

    floatx4 macc[8];
#pragma unroll
    for (int ct = 0; ct < 8; ++ct) macc[ct] = (floatx4){0.f, 0.f, 0.f, 0.f};
    float l0 = 0.f;
    const float rsd = 0.08838834764831845f;   // 1/sqrt(128)

    const int irange = N / NSplit;
    const int i0 = split * irange;
    const int nsteps = irange >> 5;

    // staging lane decomposition (pre-swizzled global chunk)
    const int kr = (w << 2) + (lane >> 4);           // K row (i) 0..31
    const int kj = (lane & 15) ^ (kr & 7);           // 16B chunk of 16
    const int vc = (w << 4) + (lane >> 2);           // V row (c) 0..127
    const int vj = (lane & 3) ^ ((vc >> 1) & 3);     // 16B chunk of 4
    const int ar0 = (w << 3) + (lane >> 3);          // att row 0..63 (pass 0)
    const int aj  = (lane & 7) ^ (ar0 & 7);          // 16B chunk of 8 (same both passes)
    const float* arp0 = attb + (size_t)(obase + ar0) * N;        // pass-0 row
    const float* arp1 = attb + (size_t)(obase + 64 + ar0) * N;   // pass-1 row

    // wave-private P strip ([o=q][i 32] bf16, 16B-unit XOR (q&3) swizzle)
    unsigned short* Pw = &P_l[w][0];
    char* pw0 = (char*)Pw + q * 64 + ((((g >> 1)) ^ (q & 3)) << 4) + ((g & 1) << 3);
    char* pw1 = (char*)Pw + q * 64 + (((2 + (g >> 1)) ^ (q & 3)) << 4) + ((g & 1) << 3);
    const char* pr = (const char*)Pw + q * 64 + ((g ^ (q & 3)) << 4);

    // prologue: stage step 0
    STAGE_ALL(0, i0)
    __syncthreads();

    for (int st = 0; st < nsteps; st += 2) {
        {   // even step: compute buf 0, stage buf 1
            if (st + 1 < nsteps) { STAGE_ALL(1, i0 + (st + 1) * 32) }
            ATT_STEP(0)
            __syncthreads();
        }
        {   // odd step: compute buf 1, stage buf 0
            if (st + 2 < nsteps) { STAGE_ALL(0, i0 + (st + 2) * 32) }
            ATT_STEP(1)
            __syncthreads();
        }
    }

    // partial denominator (wave-private o's)
    l0 += __shfl_xor(l0, 16);
    l0 += __shfl_xor(l0, 32);
    if (lane < 16)
        pl[(size_t)(split * bs + b) * N + wo + lane] = l0;

    // partial message: wave-exclusive (c, o) -> direct stores
    float* pbase = pmsg + (size_t)(split * bs + b) * 128 * N;
#pragma unroll
    for (int ct = 0; ct < 8; ++ct) {
        int c = ct * 16 + g * 4;
#pragma unroll
        for (int r = 0; r < 4; ++r)
            pbase[(size_t)(c + r) * N + wo + q] = macc[ct][r];
    }
}

// ---------------- Kernel 3: fused NSPLIT-way merge + MLP + residual ----------------
template<int NSPLIT>
__global__ __launch_bounds__(256) void mlp_kernel(
    const float* __restrict__ pmsg, const float* __restrict__ pl,
    const float* __restrict__ feat,
    const float* __restrict__ W1, const float* __restrict__ b1,
    const float* __restrict__ g1, const float* __restrict__ be1,
    const float* __restrict__ m1, const float* __restrict__ v1,
    const float* __restrict__ W2, const float* __restrict__ b2,
    const float* __restrict__ g2, const float* __restrict__ be2,
    const float* __restrict__ m2, const float* __restrict__ v2,
    const float* __restrict__ W3, const float* __restrict__ b3,
    float* __restrict__ out, int N, int bs)
{
    const int b = blockIdx.y;
    const int nb = blockIdx.x * 32;
    const int t = threadIdx.x;
    const int n_l = t & 31, og = t >> 5;   // 8 groups
    const float EPS = 1e-5f;

    __shared__ float msg_s[128][32];
    __shared__ float h1_s[64][32];
    __shared__ float h2_s[64][32];
    __shared__ float linv_s[32];

    if (t < 32) {
        float s = 0.f;
#pragma unroll
        for (int k = 0; k < NSPLIT; ++k)
            s += pl[(size_t)(k * bs + b) * N + nb + t];
        linv_s[t] = 1.f / s;
    }
    __syncthreads();

    // phase 0: merge partials into LDS msg tile (float4, fully unrolled)
#pragma unroll
    for (int r = 0; r < 4; ++r) {
        int idx = t + r * 256;            // 0..1023 float4 slots
        int c = idx >> 3, n4 = (idx & 7) * 4;
        float4 s = make_float4(0.f, 0.f, 0.f, 0.f);
#pragma unroll
        for (int k = 0; k < NSPLIT; ++k) {
            float4 v = *(const float4*)(pmsg + (size_t)(k * bs + b) * 128 * N
                                        + (size_t)c * N + nb + n4);
            s.x += v.x; s.y += v.y; s.z += v.z; s.w += v.w;
        }
        float4 li = *(const float4*)&linv_s[n4];
        msg_s[c][n4 + 0] = s.x * li.x;
        msg_s[c][n4 + 1] = s.y * li.y;
        msg_s[c][n4 + 2] = s.z * li.z;
        msg_s[c][n4 + 3] = s.w * li.w;
    }
    __syncthreads();

    float acc[8];
#pragma unroll
    for (int i = 0; i < 8; ++i) acc[i] = 0.f;
    for (int c4 = 0; c4 < 128; c4 += 4) {
        float f0 = msg_s[c4 + 0][n_l], f1 = msg_s[c4 + 1][n_l];
        float f2 = msg_s[c4 + 2][n_l], f3 = msg_s[c4 + 3][n_l];
#pragma unroll
        for (int oi = 0; oi < 8; ++oi) {
            float4 wv = *(const float4*)(W1 + (og * 8 + oi) * 128 + c4);
            acc[oi] += wv.x * f0 + wv.y * f1 + wv.z * f2 + wv.w * f3;
        }
    }
#pragma unroll
    for (int oi = 0; oi < 8; ++oi) {
        int o = og * 8 + oi;
        float inv = g1[o] / sqrtf(v1[o] + EPS);
        float val = (acc[oi] + b1[o]) * inv + (be1[o] - m1[o] * inv);
        h1_s[o][n_l] = fmaxf(val, 0.f);
    }
    __syncthreads();

    float acc2[8];
#pragma unroll
    for (int i = 0; i < 8; ++i) acc2[i] = 0.f;
    for (int c4 = 0; c4 < 64; c4 += 4) {
        float f0 = h1_s[c4 + 0][n_l], f1 = h1_s[c4 + 1][n_l];
        float f2 = h1_s[c4 + 2][n_l], f3 = h1_s[c4 + 3][n_l];
#pragma unroll
        for (int oi = 0; oi < 8; ++oi) {
            float4 wv = *(const float4*)(W2 + (og * 8 + oi) * 64 + c4);
            acc2[oi] += wv.x * f0 + wv.y * f1 + wv.z * f2 + wv.w * f3;
        }
    }
#pragma unroll
    for (int oi = 0; oi < 8; ++oi) {
        int o = og * 8 + oi;
        float inv = g2[o] / sqrtf(v2[o] + EPS);
        float val = (acc2[oi] + b2[o]) * inv + (be2[o] - m2[o] * inv);
        h2_s[o][n_l] = fmaxf(val, 0.f);
    }
    __syncthreads();

    float acc3[16];
#pragma unroll
    for (int i = 0; i < 16; ++i) acc3[i] = 0.f;
    for (int c4 = 0; c4 < 64; c4 += 4) {
        float f0 = h2_s[c4 + 0][n_l], f1 = h2_s[c4 + 1][n_l];
        float f2 = h2_s[c4 + 2][n_l], f3 = h2_s[c4 + 3][n_l];
#pragma unroll
        for (int oi = 0; oi < 16; ++oi) {
            float4 wv = *(const float4*)(W3 + (og * 16 + oi) * 64 + c4);
            acc3[oi] += wv.x * f0 + wv.y * f1 + wv.z * f2 + wv.w * f3;
        }
    }
#pragma unroll
    for (int oi = 0; oi < 16; ++oi) {
        int o = og * 16 + oi;
        size_t idx = (size_t)(b * 128 + o) * N + nb + n_l;
        out[idx] = feat[idx] + acc3[oi] + b3[o];
    }
}

extern "C" void kernel_launch(void* const* d_in, const int* in_sizes, int n_in,
                              void* d_out, int out_size, void* d_ws, size_t ws_size,
                              hipStream_t stream)
{
    const float* feat = (const float*)d_in[0];
    const float* att  = (const float*)d_in[1];
    const float* Wq = (const float*)d_in[2];  const float* bq = (const float*)d_in[3];
    const float* Wk = (const float*)d_in[4];  const float* bk = (const float*)d_in[5];
    const float* Wv = (const float*)d_in[6];  const float* bv = (const float*)d_in[7];
    const float* W1 = (const float*)d_in[8];  const float* b1 = (const float*)d_in[9];
    const float* g1 = (const float*)d_in[10]; const float* be1 = (const float*)d_in[11];
    const float* m1 = (const float*)d_in[12]; const float* v1 = (const float*)d_in[13];
    const float* W2 = (const float*)d_in[14]; const float* b2 = (const float*)d_in[15];
    const float* g2 = (const float*)d_in[16]; const float* be2 = (const float*)d_in[17];
    const float* m2 = (const float*)d_in[18]; const float* v2 = (const float*)d_in[19];
    const float* W3 = (const float*)d_in[20]; const float* b3 = (const float*)d_in[21];

    long long bsN = (long long)in_sizes[0] / 128;   // bs*N
    long long NN  = (long long)in_sizes[1];         // bs*N*N
    int N  = (int)(NN / bsN);
    int bs = (int)(bsN / N);

    // workspace layout (NSplit adaptive to ws_size)
    size_t qkvBytes = (size_t)3 * bs * N * 128 * 2;
    int NSplit = 8;
    while (NSplit > 1) {
        size_t need = qkvBytes + (size_t)NSplit * bs * 128 * N * 4
                    + (size_t)NSplit * bs * N * 4;
        if (need <= ws_size) break;
        NSplit >>= 1;
    }

    char* ws = (char*)d_ws;
    unsigned short* Qt = (unsigned short*)ws;            // bs*N*128 bf16
    unsigned short* Kt = Qt + (size_t)bs * N * 128;      // bs*N*128 bf16
    unsigned short* Vb = Kt + (size_t)bs * N * 128;      // bs*128*N bf16
    float* pmsg = (float*)(Vb + (size_t)bs * N * 128);   // NSplit*bs*128*N f32
    float* pl   = pmsg + (size_t)NSplit * bs * 128 * N;  // NSplit*bs*N f32

    dim3 grid1(N / 64, 2, bs);
    qkv_kernel<<<grid1, 256, 0, stream>>>(feat, Wq, bq, Wk, bk, Wv, bv, Qt, Kt, Vb, N);

    dim3 grid2(N / 128, NSplit, bs);
    attn_kernel<<<grid2, 512, 0, stream>>>(Qt, Kt, Vb, att, pmsg, pl, N, bs);

    dim3 grid3(N / 32, bs);
    switch (NSplit) {
    case 8:
        mlp_kernel<8><<<grid3, 256, 0, stream>>>(pmsg, pl, feat,
            W1, b1, g1, be1, m1, v1, W2, b2, g2, be2, m2, v2, W3, b3,
            (float*)d_out, N, bs);
        break;
    case 4:
        mlp_kernel<4><<<grid3, 256, 0, stream>>>(pmsg, pl, feat,
            W1, b1, g1, be1, m1, v1, W2, b2, g2, be2, m2, v2, W3, b3,
            (float*)d_out, N, bs);
        break;
    case 2:
        mlp_kernel<2><<<grid3, 256, 0, stream>>>(pmsg, pl, feat,
            W1, b1, g1, be1, m1, v1, W2, b2, g2, be2, m2, v2, W3, b3,
            (float*)d_out, N, bs);
        break;
    default:
        mlp_kernel<1><<<grid3, 256, 0, stream>>>(pmsg, pl, feat,
            W1, b1, g1, be1, m1, v1, W2, b2, g2, be2, m2, v2, W3, b3,
            (float*)d_out, N, bs);
        break;
    }
}

// Round 15
// 73.531 us; speedup vs baseline: 1.0636x; 1.0220x over previous
//
#include <hip/hip_runtime.h>
#include <hip/hip_bf16.h>
#include <math.h>

typedef __attribute__((ext_vector_type(8))) short short8;   // bf16x8 MFMA frag
typedef __attribute__((ext_vector_type(4))) float floatx4;  // f32x4 MFMA acc
typedef float __attribute__((ext_vector_type(4))) f32x4;

static __device__ __forceinline__ unsigned short f2bf(float x) {
    union { float f; unsigned u; } v; v.f = x;
    unsigned r = v.u + 0x7FFFu + ((v.u >> 16) & 1u);
    return (unsigned short)(r >> 16);
}
static __device__ __forceinline__ unsigned packbf2(float a, float b) {
    return (unsigned)f2bf(a) | ((unsigned)f2bf(b) << 16);
}
static __device__ __forceinline__ float bf2f(unsigned short x) {
    union { unsigned u; float f; } v; v.u = (unsigned)x << 16; return v.f;
}

// ---------------- Kernel 1: QKV projections via MFMA ----------------
__global__ __launch_bounds__(256) void qkv_kernel(
    const float* __restrict__ feat,
    const float* __restrict__ Wq, const float* __restrict__ bq,
    const float* __restrict__ Wk, const float* __restrict__ bk,
    const float* __restrict__ Wv, const float* __restrict__ bv,
    unsigned short* __restrict__ Qt, unsigned short* __restrict__ Kt,
    unsigned short* __restrict__ Vb, int N)
{
    const int n0 = blockIdx.x * 64;
    const int oh = blockIdx.y;           // o-half (64 o's)
    const int b  = blockIdx.z;
    const int t = threadIdx.x;
    const int w = t >> 6, lane = t & 63, g = lane >> 4, q = lane & 15;

    __shared__ __align__(16) unsigned ft[64 * 64];   // [n][c2 swz]
    __shared__ __align__(16) unsigned wl[64 * 64];   // [o_loc][c2 swz]

    const float* fb = feat + (size_t)b * 128 * N + n0;
    {
        int n = lane;
        int swz = (n & 7) << 2;
#pragma unroll
        for (int iter = 0; iter < 16; ++iter) {
            int c2 = iter * 4 + w;
            float x0 = fb[(size_t)(2 * c2) * N + n];
            float x1 = fb[(size_t)(2 * c2 + 1) * N + n];
            ft[n * 64 + (c2 ^ swz)] = packbf2(x0, x1);
        }
    }
    __syncthreads();

    short8 af[4];
    {
        int nl = w * 16 + q;
        const unsigned* base = ft + nl * 64;
        int swz = (nl & 7) << 2;
#pragma unroll
        for (int cs = 0; cs < 4; ++cs)
            af[cs] = *(const short8*)(base + ((cs * 16 + g * 4) ^ swz));
    }

    for (int p = 0; p < 3; ++p) {
        const float* W    = p == 0 ? Wq : (p == 1 ? Wk : Wv);
        const float* bias = p == 0 ? bq : (p == 1 ? bk : bv);
        const float* Wsrc = W + (size_t)oh * 64 * 128;
        __syncthreads();
        {
            int c2 = lane;
#pragma unroll
            for (int iter = 0; iter < 16; ++iter) {
                int ol = iter * 4 + w;
                float2 v = *(const float2*)(Wsrc + ol * 128 + c2 * 2);
                wl[ol * 64 + (c2 ^ ((ol & 7) << 2))] = packbf2(v.x, v.y);
            }
        }
        __syncthreads();

#pragma unroll
        for (int ot = 0; ot < 4; ++ot) {
            short8 wf[4];
            {
                const unsigned* basep = wl + (ot * 16 + q) * 64;
                int swz = (q & 7) << 2;
#pragma unroll
                for (int cs = 0; cs < 4; ++cs)
                    wf[cs] = *(const short8*)(basep + ((cs * 16 + g * 4) ^ swz));
            }
            floatx4 acc = {0.f, 0.f, 0.f, 0.f};
            if (p < 2) {
#pragma unroll
                for (int cs = 0; cs < 4; ++cs)
                    acc = __builtin_amdgcn_mfma_f32_16x16x32_bf16(af[cs], wf[cs], acc, 0, 0, 0);
                int o = oh * 64 + ot * 16 + q;
                float bo = bias[o];
                unsigned short* T = (p == 0 ? Qt : Kt) + (size_t)b * N * 128;
#pragma unroll
                for (int rr = 0; rr < 4; ++rr) {
                    int n = n0 + w * 16 + g * 4 + rr;
                    T[(size_t)n * 128 + o] = f2bf(acc[rr] + bo);
                }
            } else {
#pragma unroll
                for (int cs = 0; cs < 4; ++cs)
                    acc = __builtin_amdgcn_mfma_f32_16x16x32_bf16(wf[cs], af[cs], acc, 0, 0, 0);
                int n = n0 + w * 16 + q;
#pragma unroll
                for (int rr = 0; rr < 4; ++rr) {
                    int o = oh * 64 + ot * 16 + g * 4 + rr;
                    Vb[((size_t)b * 128 + o) * N + n] = f2bf(acc[rr] + bias[o]);
                }
            }
        }
    }
}

// ---------------- Kernel 2: block-cooperative flash attention v3.2 ----------------
// r14 body (best measured) + XCD-bijective flat grid (K/V per-XCD L2 fit) +
// bf16 partial outputs (halved partial traffic, L3 pressure relief).
#define STAGE_ALL(BUF, IB)                                                                 \
    __builtin_amdgcn_global_load_lds(                                                      \
        (const void*)(Kb + (size_t)((IB) + kr) * 128 + (kj << 3)),                         \
        (void*)((char*)&K_l[BUF][0] + (w << 10) + (lane << 4)), 16, 0, 0);                 \
    __builtin_amdgcn_global_load_lds(                                                      \
        (const void*)(Vbp + (size_t)vc * N + (IB) + (vj << 3)),                            \
        (void*)((char*)&V_l[BUF][0] + (w << 10) + (lane << 4)), 16, 0, 0);                 \
    __builtin_amdgcn_global_load_lds(                                                      \
        (const void*)(arp0 + (IB) + (aj << 2)),                                            \
        (void*)((char*)&att_l[BUF][0] + (w << 10) + (lane << 4)), 16, 0, 0);               \
    __builtin_amdgcn_global_load_lds(                                                      \
        (const void*)(arp1 + (IB) + (aj << 2)),                                            \
        (void*)((char*)&att_l[BUF][0] + 8192 + (w << 10) + (lane << 4)), 16, 0, 0);

#define ATT_STEP(BUF)                                                                      \
  {                                                                                        \
    const unsigned short* Kl = &K_l[BUF][0];                                               \
    floatx4 s0 = {0.f,0.f,0.f,0.f}, s1 = {0.f,0.f,0.f,0.f};                                \
    __builtin_amdgcn_s_setprio(1);                                                         \
    _Pragma("unroll")                                                                      \
    for (int cs = 0; cs < 4; ++cs) {                                                       \
        short8 kf0 = *(const short8*)(Kl + q * 128 + ((((cs << 2) + g) ^ (q & 7)) << 3));  \
        short8 kf1 = *(const short8*)(Kl + (16 + q) * 128 + ((((cs << 2) + g) ^ (q & 7)) << 3)); \
        s0 = __builtin_amdgcn_mfma_f32_16x16x32_bf16(kf0, qf[cs], s0, 0, 0, 0);            \
        s1 = __builtin_amdgcn_mfma_f32_16x16x32_bf16(kf1, qf[cs], s1, 0, 0, 0);            \
    }                                                                                      \
    __builtin_amdgcn_s_setprio(0);                                                         \
    const float* Al = &att_l[BUF][0];                                                      \
    f32x4 av0 = *(const f32x4*)(Al + (w * 16 + q) * 32 + ((g ^ (q & 7)) << 2));            \
    f32x4 av1 = *(const f32x4*)(Al + (w * 16 + q) * 32 + (((4 + g) ^ (q & 7)) << 2));      \
    float p0 = __expf(s0[0] * rsd * av0[0]);                                               \
    float p1 = __expf(s0[1] * rsd * av0[1]);                                               \
    float p2 = __expf(s0[2] * rsd * av0[2]);                                               \
    float p3 = __expf(s0[3] * rsd * av0[3]);                                               \
    float p4 = __expf(s1[0] * rsd * av1[0]);                                               \
    float p5 = __expf(s1[1] * rsd * av1[1]);                                               \
    float p6 = __expf(s1[2] * rsd * av1[2]);                                               \
    float p7 = __expf(s1[3] * rsd * av1[3]);                                               \
    l0 += ((p0 + p1) + (p2 + p3)) + ((p4 + p5) + (p6 + p7));                               \
    unsigned u01, u23, u45, u67;                                                           \
    asm("v_cvt_pk_bf16_f32 %0, %1, %2" : "=v"(u01) : "v"(p0), "v"(p1));                    \
    asm("v_cvt_pk_bf16_f32 %0, %1, %2" : "=v"(u23) : "v"(p2), "v"(p3));                    \
    asm("v_cvt_pk_bf16_f32 %0, %1, %2" : "=v"(u45) : "v"(p4), "v"(p5));                    \
    asm("v_cvt_pk_bf16_f32 %0, %1, %2" : "=v"(u67) : "v"(p6), "v"(p7));                    \
    *(uint2*)pw0 = make_uint2(u01, u23);                                                   \
    *(uint2*)pw1 = make_uint2(u45, u67);                                                   \
    short8 pf = *(const short8*)pr;                                                        \
    const unsigned short* Vl = &V_l[BUF][0];                                               \
    __builtin_amdgcn_s_setprio(1);                                                         \
    _Pragma("unroll")                                                                      \
    for (int ct = 0; ct < 8; ++ct) {                                                       \
        int c = ct * 16 + q;                                                               \
        short8 vf = *(const short8*)(Vl + c * 32 + ((g ^ ((c >> 1) & 3)) << 3));           \
        macc[ct] = __builtin_amdgcn_mfma_f32_16x16x32_bf16(vf, pf, macc[ct], 0, 0, 0);     \
    }                                                                                      \
    __builtin_amdgcn_s_setprio(0);                                                         \
  }

__global__ __launch_bounds__(512) void attn_kernel(
    const unsigned short* __restrict__ Qt, const unsigned short* __restrict__ Kt,
    const unsigned short* __restrict__ Vb, const float* __restrict__ att,
    unsigned short* __restrict__ pmsg, float* __restrict__ pl,
    int N, int bs, int nbx, int nsplit)
{
    // XCD-bijective swizzle of the flat grid: blocks of one batch land on
    // consecutive dispatch slots mod 8 -> each XCD's L2 holds ONE batch's K/V (4MB).
    const int nwg = gridDim.x;
    int flat = blockIdx.x;
    int orig = ((nwg & 7) == 0) ? ((flat & 7) * (nwg >> 3) + (flat >> 3)) : flat;
    const int obx = orig % nbx;
    const int rest = orig / nbx;
    const int split = rest % nsplit;
    const int b = rest / nsplit;
    const int obase = obx * 128;
    const int t = threadIdx.x;
    const int w = t >> 6, lane = t & 63, g = lane >> 4, q = lane & 15;

    __shared__ __align__(16) unsigned short K_l[2][32 * 128];  // 16 KB [i][c] swz
    __shared__ __align__(16) unsigned short V_l[2][128 * 32];  // 16 KB [c][i] swz
    __shared__ __align__(16) float att_l[2][128 * 32];         // 32 KB [o][i] swz
    __shared__ __align__(16) unsigned short P_l[8][16 * 32];   // 8 KB wave-private

    const unsigned short* Qb  = Qt + (size_t)b * N * 128;
    const unsigned short* Kb  = Kt + (size_t)b * N * 128;
    const unsigned short* Vbp = Vb + (size_t)b * 128 * N;
    const float* attb = att + (size_t)b * N * N;
    const int wo = obase + w * 16;                 // wave's o-base

    // Q B-frags for o = wo + q
    short8 qf[4];
#pragma unroll
    for (int cs = 0; cs < 4; ++cs)
        qf[cs] = *(const short8*)(Qb + (size_t)(wo + q) * 128 + cs * 32 + g * 8);

    floatx4 macc[8];
#pragma unroll
    for (int ct = 0; ct < 8; ++ct) macc[ct] = (floatx4){0.f, 0.f, 0.f, 0.f};
    float l0 = 0.f;
    const float rsd = 0.08838834764831845f;   // 1/sqrt(128)

    const int irange = N / nsplit;
    const int i0 = split * irange;
    const int nsteps = irange >> 5;

    // staging lane decomposition (pre-swizzled global chunk)
    const int kr = (w << 2) + (lane >> 4);           // K row (i) 0..31
    const int kj = (lane & 15) ^ (kr & 7);           // 16B chunk of 16
    const int vc = (w << 4) + (lane >> 2);           // V row (c) 0..127
    const int vj = (lane & 3) ^ ((vc >> 1) & 3);     // 16B chunk of 4
    const int ar0 = (w << 3) + (lane >> 3);          // att row 0..63 (pass 0)
    const int aj  = (lane & 7) ^ (ar0 & 7);          // 16B chunk of 8 (same both passes)
    const float* arp0 = attb + (size_t)(obase + ar0) * N;        // pass-0 row
    const float* arp1 = attb + (size_t)(obase + 64 + ar0) * N;   // pass-1 row

    // wave-private P strip ([o=q][i 32] bf16, 16B-unit XOR (q&3) swizzle)
    unsigned short* Pw = &P_l[w][0];
    char* pw0 = (char*)Pw + q * 64 + ((((g >> 1)) ^ (q & 3)) << 4) + ((g & 1) << 3);
    char* pw1 = (char*)Pw + q * 64 + (((2 + (g >> 1)) ^ (q & 3)) << 4) + ((g & 1) << 3);
    const char* pr = (const char*)Pw + q * 64 + ((g ^ (q & 3)) << 4);

    // prologue: stage step 0
    STAGE_ALL(0, i0)
    __syncthreads();

    for (int st = 0; st < nsteps; st += 2) {
        {   // even step: compute buf 0, stage buf 1
            if (st + 1 < nsteps) { STAGE_ALL(1, i0 + (st + 1) * 32) }
            ATT_STEP(0)
            __syncthreads();
        }
        {   // odd step: compute buf 1, stage buf 0
            if (st + 2 < nsteps) { STAGE_ALL(0, i0 + (st + 2) * 32) }
            ATT_STEP(1)
            __syncthreads();
        }
    }

    // partial denominator (wave-private o's)
    l0 += __shfl_xor(l0, 16);
    l0 += __shfl_xor(l0, 32);
    if (lane < 16)
        pl[(size_t)(split * bs + b) * N + wo + lane] = l0;

    // partial message (bf16): wave-exclusive (c, o) -> direct stores
    unsigned short* pbase = pmsg + (size_t)(split * bs + b) * 128 * N;
#pragma unroll
    for (int ct = 0; ct < 8; ++ct) {
        int c = ct * 16 + g * 4;
#pragma unroll
        for (int r = 0; r < 4; ++r)
            pbase[(size_t)(c + r) * N + wo + q] = f2bf(macc[ct][r]);
    }
}

// ---------------- Kernel 3: fused NSPLIT-way merge + MLP + residual ----------------
template<int NSPLIT>
__global__ __launch_bounds__(256) void mlp_kernel(
    const unsigned short* __restrict__ pmsg, const float* __restrict__ pl,
    const float* __restrict__ feat,
    const float* __restrict__ W1, const float* __restrict__ b1,
    const float* __restrict__ g1, const float* __restrict__ be1,
    const float* __restrict__ m1, const float* __restrict__ v1,
    const float* __restrict__ W2, const float* __restrict__ b2,
    const float* __restrict__ g2, const float* __restrict__ be2,
    const float* __restrict__ m2, const float* __restrict__ v2,
    const float* __restrict__ W3, const float* __restrict__ b3,
    float* __restrict__ out, int N, int bs)
{
    const int b = blockIdx.y;
    const int nb = blockIdx.x * 32;
    const int t = threadIdx.x;
    const int n_l = t & 31, og = t >> 5;   // 8 groups
    const float EPS = 1e-5f;

    __shared__ float msg_s[128][32];
    __shared__ float h1_s[64][32];
    __shared__ float h2_s[64][32];
    __shared__ float linv_s[32];

    if (t < 32) {
        float s = 0.f;
#pragma unroll
        for (int k = 0; k < NSPLIT; ++k)
            s += pl[(size_t)(k * bs + b) * N + nb + t];
        linv_s[t] = 1.f / s;
    }
    __syncthreads();

    // phase 0: merge bf16 partials into LDS msg tile (ushort4, fully unrolled)
#pragma unroll
    for (int r = 0; r < 4; ++r) {
        int idx = t + r * 256;            // 0..1023 quad slots
        int c = idx >> 3, n4 = (idx & 7) * 4;
        float s0 = 0.f, s1 = 0.f, s2 = 0.f, s3 = 0.f;
#pragma unroll
        for (int k = 0; k < NSPLIT; ++k) {
            ushort4 v = *(const ushort4*)(pmsg + (size_t)(k * bs + b) * 128 * N
                                          + (size_t)c * N + nb + n4);
            s0 += bf2f(v.x); s1 += bf2f(v.y); s2 += bf2f(v.z); s3 += bf2f(v.w);
        }
        float4 li = *(const float4*)&linv_s[n4];
        msg_s[c][n4 + 0] = s0 * li.x;
        msg_s[c][n4 + 1] = s1 * li.y;
        msg_s[c][n4 + 2] = s2 * li.z;
        msg_s[c][n4 + 3] = s3 * li.w;
    }
    __syncthreads();

    float acc[8];
#pragma unroll
    for (int i = 0; i < 8; ++i) acc[i] = 0.f;
    for (int c4 = 0; c4 < 128; c4 += 4) {
        float f0 = msg_s[c4 + 0][n_l], f1 = msg_s[c4 + 1][n_l];
        float f2 = msg_s[c4 + 2][n_l], f3 = msg_s[c4 + 3][n_l];
#pragma unroll
        for (int oi = 0; oi < 8; ++oi) {
            float4 wv = *(const float4*)(W1 + (og * 8 + oi) * 128 + c4);
            acc[oi] += wv.x * f0 + wv.y * f1 + wv.z * f2 + wv.w * f3;
        }
    }
#pragma unroll
    for (int oi = 0; oi < 8; ++oi) {
        int o = og * 8 + oi;
        float inv = g1[o] / sqrtf(v1[o] + EPS);
        float val = (acc[oi] + b1[o]) * inv + (be1[o] - m1[o] * inv);
        h1_s[o][n_l] = fmaxf(val, 0.f);
    }
    __syncthreads();

    float acc2[8];
#pragma unroll
    for (int i = 0; i < 8; ++i) acc2[i] = 0.f;
    for (int c4 = 0; c4 < 64; c4 += 4) {
        float f0 = h1_s[c4 + 0][n_l], f1 = h1_s[c4 + 1][n_l];
        float f2 = h1_s[c4 + 2][n_l], f3 = h1_s[c4 + 3][n_l];
#pragma unroll
        for (int oi = 0; oi < 8; ++oi) {
            float4 wv = *(const float4*)(W2 + (og * 8 + oi) * 64 + c4);
            acc2[oi] += wv.x * f0 + wv.y * f1 + wv.z * f2 + wv.w * f3;
        }
    }
#pragma unroll
    for (int oi = 0; oi < 8; ++oi) {
        int o = og * 8 + oi;
        float inv = g2[o] / sqrtf(v2[o] + EPS);
        float val = (acc2[oi] + b2[o]) * inv + (be2[o] - m2[o] * inv);
        h2_s[o][n_l] = fmaxf(val, 0.f);
    }
    __syncthreads();

    float acc3[16];
#pragma unroll
    for (int i = 0; i < 16; ++i) acc3[i] = 0.f;
    for (int c4 = 0; c4 < 64; c4 += 4) {
        float f0 = h2_s[c4 + 0][n_l], f1 = h2_s[c4 + 1][n_l];
        float f2 = h2_s[c4 + 2][n_l], f3 = h2_s[c4 + 3][n_l];
#pragma unroll
        for (int oi = 0; oi < 16; ++oi) {
            float4 wv = *(const float4*)(W3 + (og * 16 + oi) * 64 + c4);
            acc3[oi] += wv.x * f0 + wv.y * f1 + wv.z * f2 + wv.w * f3;
        }
    }
#pragma unroll
    for (int oi = 0; oi < 16; ++oi) {
        int o = og * 16 + oi;
        size_t idx = (size_t)(b * 128 + o) * N + nb + n_l;
        out[idx] = feat[idx] + acc3[oi] + b3[o];
    }
}

extern "C" void kernel_launch(void* const* d_in, const int* in_sizes, int n_in,
                              void* d_out, int out_size, void* d_ws, size_t ws_size,
                              hipStream_t stream)
{
    const float* feat = (const float*)d_in[0];
    const float* att  = (const float*)d_in[1];
    const float* Wq = (const float*)d_in[2];  const float* bq = (const float*)d_in[3];
    const float* Wk = (const float*)d_in[4];  const float* bk = (const float*)d_in[5];
    const float* Wv = (const float*)d_in[6];  const float* bv = (const float*)d_in[7];
    const float* W1 = (const float*)d_in[8];  const float* b1 = (const float*)d_in[9];
    const float* g1 = (const float*)d_in[10]; const float* be1 = (const float*)d_in[11];
    const float* m1 = (const float*)d_in[12]; const float* v1 = (const float*)d_in[13];
    const float* W2 = (const float*)d_in[14]; const float* b2 = (const float*)d_in[15];
    const float* g2 = (const float*)d_in[16]; const float* be2 = (const float*)d_in[17];
    const float* m2 = (const float*)d_in[18]; const float* v2 = (const float*)d_in[19];
    const float* W3 = (const float*)d_in[20]; const float* b3 = (const float*)d_in[21];

    long long bsN = (long long)in_sizes[0] / 128;   // bs*N
    long long NN  = (long long)in_sizes[1];         // bs*N*N
    int N  = (int)(NN / bsN);
    int bs = (int)(bsN / N);

    // workspace layout (NSplit adaptive to ws_size); bf16 partials
    size_t qkvBytes = (size_t)3 * bs * N * 128 * 2;
    int NSplit = 8;
    while (NSplit > 1) {
        size_t need = qkvBytes + (size_t)NSplit * bs * 128 * N * 2
                    + (size_t)NSplit * bs * N * 4;
        if (need <= ws_size) break;
        NSplit >>= 1;
    }

    char* ws = (char*)d_ws;
    unsigned short* Qt = (unsigned short*)ws;             // bs*N*128 bf16
    unsigned short* Kt = Qt + (size_t)bs * N * 128;       // bs*N*128 bf16
    unsigned short* Vb = Kt + (size_t)bs * N * 128;       // bs*128*N bf16
    unsigned short* pmsg = Vb + (size_t)bs * N * 128;     // NSplit*bs*128*N bf16
    float* pl = (float*)(pmsg + (size_t)NSplit * bs * 128 * N);  // NSplit*bs*N f32

    dim3 grid1(N / 64, 2, bs);
    qkv_kernel<<<grid1, 256, 0, stream>>>(feat, Wq, bq, Wk, bk, Wv, bv, Qt, Kt, Vb, N);

    int nbx = N / 128;
    dim3 grid2(nbx * NSplit * bs);
    attn_kernel<<<grid2, 512, 0, stream>>>(Qt, Kt, Vb, att, pmsg, pl, N, bs, nbx, NSplit);

    dim3 grid3(N / 32, bs);
    switch (NSplit) {
    case 8:
        mlp_kernel<8><<<grid3, 256, 0, stream>>>(pmsg, pl, feat,
            W1, b1, g1, be1, m1, v1, W2, b2, g2, be2, m2, v2, W3, b3,
            (float*)d_out, N, bs);
        break;
    case 4:
        mlp_kernel<4><<<grid3, 256, 0, stream>>>(pmsg, pl, feat,
            W1, b1, g1, be1, m1, v1, W2, b2, g2, be2, m2, v2, W3, b3,
            (float*)d_out, N, bs);
        break;
    case 2:
        mlp_kernel<2><<<grid3, 256, 0, stream>>>(pmsg, pl, feat,
            W1, b1, g1, be1, m1, v1, W2, b2, g2, be2, m2, v2, W3, b3,
            (float*)d_out, N, bs);
        break;
    default:
        mlp_kernel<1><<<grid3, 256, 0, stream>>>(pmsg, pl, feat,
            W1, b1, g1, be1, m1, v1, W2, b2, g2, be2, m2, v2, W3, b3,
            (float*)d_out, N, bs);
        break;
    }
}